// Round 5
// baseline (450.240 us; speedup 1.0000x reference)
//
#include <hip/hip_runtime.h>

// Problem: B=2048, C=16, S=2000, fp32.
// Reference collapses: softmax rows sum to 1 over m, so
// einsum('bcs,bcm->bcs', x, score) == x exactly. The kernel is therefore
// out = LN_c(Wp @ x[b,:,s] + bp) * gp + hp, a pure streaming op:
// 262 MB in + 262 MB out -> ~83 us roofline @ 6.3 TB/s achievable.
//
// Session ledger (timed region = 2 harness poison-fills ~322us + kernel):
//   R1 float2 (256,4) all-16, nt:    435.5 total (~111 us kernel)
//   R2 float2 (256,8) split, nt:     437.3   occupancy: falsified
//   R3 float4 (256,4) split, nt:     442.1   VMEM width: falsified
//   R4 = R1 + centered-W, nt:        434.9   VALU tail: immaterial
// R5 = R4 with nontemporal hints REMOVED (single-axis A/B). R0->R1's -21us
// bundled float2 + nt; nt was never isolated. The 6.3-6.5 TB/s reference
// streams (harness fill, m13 copy) use plain cached accesses through
// L2/MALL; nt write-around may degrade HBM burst combining. If >=430us,
// nt is neutral and the session declares roofline.

#define NC 16          // channels
#define NS 2000        // sequence
#define SV2 (NS / 2)   // 1000 float2 per (b,c) row
#define EPS 1e-5f
#define BLK 256

typedef float f32x2 __attribute__((ext_vector_type(2)));
typedef float f32x4 __attribute__((ext_vector_type(4)));

__global__ __launch_bounds__(BLK, 4) void chanattn_fused(
    const float* __restrict__ x,
    const float* __restrict__ Wp,
    const float* __restrict__ bp,
    const float* __restrict__ gp,
    const float* __restrict__ hp,
    float* __restrict__ out,
    unsigned total)        // B * SV2
{
    // sW[cp][c] = Wp[c][cp] (transposed; c contiguous so one f32x4 read
    // grabs 4 output channels). Then center: sW[cp][c] -= mean_c(sW[cp][:]),
    // sbc[c] = b[c] - mean(b), making the LN mean identically 0. All
    // main-loop reads are same-address -> LDS broadcast, conflict-free.
    __shared__ __align__(16) float sW[NC * NC];
    __shared__ float sm[NC];                  // per-cp column mean of W^T
    __shared__ float sb[NC], sbc[NC], sg[NC], sh[NC];
    const int tid = threadIdx.x;
    if (tid < NC * NC) sW[(tid & (NC - 1)) * NC + (tid >> 4)] = Wp[tid];
    if (tid < NC) { sb[tid] = bp[tid]; sg[tid] = gp[tid]; sh[tid] = hp[tid]; }
    __syncthreads();
    if (tid < NC) {
        float s = 0.f;
#pragma unroll
        for (int j = 0; j < NC; ++j) s += sW[tid * NC + j];
        sm[tid] = s * (1.0f / NC);
    }
    __syncthreads();
    if (tid < NC * NC) sW[tid] -= sm[tid >> 4];
    if (tid < NC) {
        float mb = 0.f;
#pragma unroll
        for (int j = 0; j < NC; ++j) mb += sb[j];
        sbc[tid] = sb[tid] - mb * (1.0f / NC);   // write to sbc: no race
    }
    __syncthreads();
    const f32x4* __restrict__ sW4 = (const f32x4*)sW;

    const unsigned t = blockIdx.x * BLK + tid;
    if (t >= total) return;
    const unsigned b  = t / SV2;       // const-division -> magic mul
    const unsigned s2 = t - b * SV2;

    const f32x2* __restrict__ px = (const f32x2*)x   + (size_t)b * (NC * SV2) + s2;
    f32x2*       __restrict__ po = (f32x2*)out       + (size_t)b * (NC * SV2) + s2;

    // 16 independent plain (cached) loads in flight per wave, 512B each,
    // perfectly coalesced. Identical shape to R4 except no nt hints.
    f32x2 xv[NC];
#pragma unroll
    for (int c = 0; c < NC; ++c)
        xv[c] = px[c * SV2];

    // y[c] = bc[c] + sum_cp Wc[c][cp] * x[cp]  -- centered, so mean(y) == 0.
    f32x2 y[NC];
#pragma unroll
    for (int c = 0; c < NC; ++c) {
        const float bb = sbc[c];
        y[c].x = bb; y[c].y = bb;
    }
#pragma unroll
    for (int cp = 0; cp < NC; ++cp) {
        const f32x2 xc = xv[cp];
#pragma unroll
        for (int k = 0; k < 4; ++k) {
            const f32x4 w = sW4[cp * 4 + k];
            y[4 * k + 0].x = fmaf(w.x, xc.x, y[4 * k + 0].x);
            y[4 * k + 0].y = fmaf(w.x, xc.y, y[4 * k + 0].y);
            y[4 * k + 1].x = fmaf(w.y, xc.x, y[4 * k + 1].x);
            y[4 * k + 1].y = fmaf(w.y, xc.y, y[4 * k + 1].y);
            y[4 * k + 2].x = fmaf(w.z, xc.x, y[4 * k + 2].x);
            y[4 * k + 2].y = fmaf(w.z, xc.y, y[4 * k + 2].y);
            y[4 * k + 3].x = fmaf(w.w, xc.x, y[4 * k + 3].x);
            y[4 * k + 3].y = fmaf(w.w, xc.y, y[4 * k + 3].y);
        }
    }

    // LayerNorm with mu == 0: var = mean(y^2), out = y*rsqrt(var+eps)*g + h.
    float vx = 0.f, vy = 0.f;
#pragma unroll
    for (int c = 0; c < NC; ++c) {
        vx = fmaf(y[c].x, y[c].x, vx);
        vy = fmaf(y[c].y, y[c].y, vy);
    }
    const float inv = 1.0f / NC;
    const float rx = rsqrtf(vx * inv + EPS);
    const float ry = rsqrtf(vy * inv + EPS);

#pragma unroll
    for (int c = 0; c < NC; ++c) {
        const float g = sg[c], h = sh[c];
        f32x2 o;
        o.x = fmaf(y[c].x * rx, g, h);
        o.y = fmaf(y[c].y * ry, g, h);
        po[c * SV2] = o;
    }
}

extern "C" void kernel_launch(void* const* d_in, const int* in_sizes, int n_in,
                              void* d_out, int out_size, void* d_ws, size_t ws_size,
                              hipStream_t stream) {
    // setup_inputs order: x, Wq, bq, gq, hq, Wk, bk, gk, hk, Wp, bp, gp, hp
    const float* x  = (const float*)d_in[0];
    const float* Wp = (const float*)d_in[9];
    const float* bp = (const float*)d_in[10];
    const float* gp = (const float*)d_in[11];
    const float* hp = (const float*)d_in[12];
    float* out = (float*)d_out;

    const unsigned B = (unsigned)(in_sizes[0] / (NC * NS));  // 2048
    const unsigned total = B * SV2;                           // 2,048,000
    const unsigned grid = (total + BLK - 1) / BLK;            // 8000
    chanattn_fused<<<grid, BLK, 0, stream>>>(x, Wp, bp, gp, hp, out, total);
}